// Round 7
// baseline (279.256 us; speedup 1.0000x reference)
//
#include <hip/hip_runtime.h>

// RNN: h_{t+1} = tanh(x_t @ W_ih^T + b_ih + b_hh + h_t @ W_hh^T), out = h_T @ fc_w^T + fc_b
// B=8192, T=512, IN=8, H=16.
//
// Round 7: split-K by 2 (32 lanes/batch, 4096 waves = 4/SIMD), FIXED roles,
// CANONICAL h placement in both rows (R6 bug fix):
//   - every lane of both 16-lane rows holds h_j (j = lane&15) at step start.
//   - q0 lane j computes output o=j, terms k=(o-R)&15, R=0..7.
//   - q1 lane j computes output o=j^8, terms k=(o-8-R)&15 = (j-R)&15, R=0..7
//     -> rotations 0..7 identical in both rows, uniform weight formula
//        wr[R] = W_hh[o][(o - 8q - R) & 15].
//   - combine with constant lane-xor-24 swizzle -> full s at every lane.
//   - q1's tanh result is h_{j^8}; one ROW-MASKED DPP (row_ror:8, row_mask=0xA)
//     rotates ONLY the q1 rows back to canonical (q0 rows keep old value).
// Weights are individual named scalars (R5 lesson: array+select -> per-step
// global reloads, VGPR=32). tanh = 1 v_exp_f32 + 1 v_rcp_f32.

#define RNN_B   8192
#define RNN_T   512
#define RNN_IN  8
#define RNN_H   16
#define TC      32                 // timesteps per x tile
#define ROWS    8                  // batch elements per 256-thread block
#define XST     264                // padded floats per xs row

// row_ror:R within 16-lane DPP row: lane i receives value from lane (i-R) & 15.
// (direction verified on HW in R3: wperm[r]=W_hh[j][(j-r)&15] passed)
template<int R>
__device__ __forceinline__ float ror16(float v) {
    return __int_as_float(__builtin_amdgcn_update_dpp(
        0, __float_as_int(v), 0x120 + R, 0xF, 0xF, false));
}

__device__ __forceinline__ float swz24(float v) {   // lane ^ 24
    return __int_as_float(__builtin_amdgcn_ds_swizzle(__float_as_int(v), 0x601F));
}

// row_ror:8 applied ONLY to rows 1,3 (q1 lanes); rows 0,2 keep old value.
__device__ __forceinline__ float fixup_q1(float v) {
    const int iv = __float_as_int(v);
    return __int_as_float(__builtin_amdgcn_update_dpp(iv, iv, 0x128, 0xA, 0xF, false));
}

__global__ __launch_bounds__(256, 4) void rnn_fused_kernel(
    const float* __restrict__ x,     // [B, T, IN]
    const float* __restrict__ W_ih,  // [H, IN]
    const float* __restrict__ W_hh,  // [H, H]
    const float* __restrict__ b_ih,  // [H]
    const float* __restrict__ b_hh,  // [H]
    const float* __restrict__ fc_w,  // [1, H]
    const float* __restrict__ fc_b,  // [1]
    float* __restrict__ out)         // [B, 1]
{
    __shared__ float xs[ROWS * XST];     // 8 rows x (32 t x 8 in), padded

    const int tid  = (int)threadIdx.x;   // 0..255
    const int lane = tid & 63;
    const int wv   = tid >> 6;           // wave in block (0..3)
    const int j    = lane & 15;          // lane within DPP row
    const int q    = (lane >> 4) & 1;    // k-half row
    const int gb   = lane >> 5;          // batch within wave (0..1)
    const int row  = 2 * wv + gb;        // batch row within block (0..7)
    const int b0   = (int)blockIdx.x * ROWS;
    const int b    = b0 + row;

    // --- per-lane weights: output o = j ^ (q<<3); term R uses column (o-8q-R)&15
    const int o  = j ^ (q << 3);
    const int c0base = (o - (q << 3)) & 15;     // = j for q1, = o for q0
    const float wr0 = W_hh[o * RNN_H + ((c0base - 0) & 15)];
    const float wr1 = W_hh[o * RNN_H + ((c0base - 1) & 15)];
    const float wr2 = W_hh[o * RNN_H + ((c0base - 2) & 15)];
    const float wr3 = W_hh[o * RNN_H + ((c0base - 3) & 15)];
    const float wr4 = W_hh[o * RNN_H + ((c0base - 4) & 15)];
    const float wr5 = W_hh[o * RNN_H + ((c0base - 5) & 15)];
    const float wr6 = W_hh[o * RNN_H + ((c0base - 6) & 15)];
    const float wr7 = W_hh[o * RNN_H + ((c0base - 7) & 15)];
    const float wi0 = W_ih[o * RNN_IN + q * 4 + 0];
    const float wi1 = W_ih[o * RNN_IN + q * 4 + 1];
    const float wi2 = W_ih[o * RNN_IN + q * 4 + 2];
    const float wi3 = W_ih[o * RNN_IN + q * 4 + 3];
    const float bias = q ? 0.0f : (b_ih[o] + b_hh[o]);

    // --- staging geometry: 512 float4 per tile, 2 per thread (verified R5) ---
    const int r0 = tid >> 6,        f0 = tid & 63;          // rows 0..3
    const int r1 = (tid + 256) >> 6;                        // rows 4..7
    const size_t goff0 = ((size_t)(b0 + r0) * RNN_T) * RNN_IN + f0 * 4;
    const size_t goff1 = ((size_t)(b0 + r1) * RNN_T) * RNN_IN + f0 * 4;
    float* const lws0 = xs + r0 * XST + f0 * 4;
    float* const lws1 = xs + r1 * XST + f0 * 4;

    float4 g0 = *(const float4*)(x + goff0);
    float4 g1 = *(const float4*)(x + goff1);
    *(float4*)lws0 = g0;
    *(float4*)lws1 = g1;

    const float* const xbase = xs + row * XST + q * 4;   // this lane's read base
    const float KTANH = 2.8853900817779268f;             // 2/ln(2)

    float h = 0.0f;    // canonical: every lane holds h_{lane&15}

    auto step = [&](const float4 xr) {
        // proj chain (this lane's half of the input dot)
        float c0 = fmaf(xr.x, wi0, bias);
        c0 = fmaf(xr.y, wi1, c0);
        c0 = fmaf(xr.z, wi2, c0);
        c0 = fmaf(xr.w, wi3, c0);
        // recurrence: 8 terms, rotations 0..7 over canonical h
        float c1 = h * wr0;
        float c2 = ror16<1>(h) * wr1;
        c1 = fmaf(ror16<2>(h), wr2, c1);
        c2 = fmaf(ror16<3>(h), wr3, c2);
        c1 = fmaf(ror16<4>(h), wr4, c1);
        c2 = fmaf(ror16<5>(h), wr5, c2);
        c1 = fmaf(ror16<6>(h), wr6, c1);
        c2 = fmaf(ror16<7>(h), wr7, c2);
        const float sp = (c0 + c1) + c2;
        const float s  = sp + swz24(sp);         // full s_o at every lane
        const float e  = __builtin_amdgcn_exp2f(s * KTANH);
        const float ht = fmaf(-2.0f, __builtin_amdgcn_rcpf(e + 1.0f), 1.0f); // h_o
        h = fixup_q1(ht);                        // q1 rows: ror8 -> canonical h_j
    };

    for (int t0 = 0; t0 < RNN_T; t0 += TC) {
        __syncthreads();                 // staged writes visible
        const bool more = (t0 + TC) < RNN_T;
        if (more) {                      // register-prefetch next tile
            g0 = *(const float4*)(x + goff0 + (size_t)(t0 + TC) * RNN_IN);
            g1 = *(const float4*)(x + goff1 + (size_t)(t0 + TC) * RNN_IN);
        }

        float4 xA = *(const float4*)(xbase);
#pragma unroll
        for (int tt = 0; tt < TC; tt += 2) {
            const float4 xB = *(const float4*)(xbase + (tt + 1) * RNN_IN);
            step(xA);
            if (tt + 2 < TC) xA = *(const float4*)(xbase + (tt + 2) * RNN_IN);
            step(xB);
        }

        if (more) {
            __syncthreads();             // all reads of current tile done
            *(float4*)lws0 = g0;
            *(float4*)lws1 = g1;
        }
    }

    // --- epilogue: all lanes hold canonical h_j; use q0 rows only ---
    float v = q ? 0.0f : h * fc_w[j];
    v += __shfl_xor(v, 1);
    v += __shfl_xor(v, 2);
    v += __shfl_xor(v, 4);
    v += __shfl_xor(v, 8);
    if ((lane & 31) == 0) out[b] = v + fc_b[0];   // lanes 0, 32
}

extern "C" void kernel_launch(void* const* d_in, const int* in_sizes, int n_in,
                              void* d_out, int out_size, void* d_ws, size_t ws_size,
                              hipStream_t stream)
{
    const float* x    = (const float*)d_in[0];
    const float* W_ih = (const float*)d_in[1];
    const float* W_hh = (const float*)d_in[2];
    const float* b_ih = (const float*)d_in[3];
    const float* b_hh = (const float*)d_in[4];
    const float* fc_w = (const float*)d_in[5];
    const float* fc_b = (const float*)d_in[6];
    float* out = (float*)d_out;

    dim3 grid(RNN_B / ROWS);   // 1024 blocks
    dim3 block(256);           // 4 waves; 4096 waves total = 4/SIMD
    rnn_fused_kernel<<<grid, block, 0, stream>>>(x, W_ih, W_hh, b_ih, b_hh, fc_w, fc_b, out);
}